// Round 6
// baseline (308.113 us; speedup 1.0000x reference)
//
#include <hip/hip_runtime.h>
#include <hip/hip_bf16.h>
#include <cmath>

// B=8, T=1024, C=768, H=12, D=64
#define B_ 8
#define T_ 1024
#define C_ 768
#define H_ 12
#define D_ 64
#define N3C 2304
#define M_ 8192   // B*T

typedef __bf16 bf16x8 __attribute__((ext_vector_type(8)));
typedef float  f32x4  __attribute__((ext_vector_type(4)));

typedef const __attribute__((address_space(1))) void* gptr_t;
typedef __attribute__((address_space(3))) void* lptr_t;

#define LOG2E 1.44269504088896f

__device__ __forceinline__ bf16x8 cvt_bf16x8(const float4& a, const float4& b) {
    bf16x8 r;
    r[0] = (__bf16)a.x; r[1] = (__bf16)a.y; r[2] = (__bf16)a.z; r[3] = (__bf16)a.w;
    r[4] = (__bf16)b.x; r[5] = (__bf16)b.y; r[6] = (__bf16)b.z; r[7] = (__bf16)b.w;
    return r;
}

// ---------------- fused pre-pass: cast x + transpose-cast both weights ----------------
__global__ __launch_bounds__(256) void prepass(const float* __restrict__ x,
                                               __bf16* __restrict__ xb,
                                               const float* __restrict__ wa,
                                               __bf16* __restrict__ wat,
                                               const float* __restrict__ wp,
                                               __bf16* __restrict__ wpt) {
    __shared__ float tile[32][33];
    const int bx = blockIdx.x, tid = threadIdx.x;
    if (bx < 3072) {
        int i = (bx * 256 + tid) * 8;
        float4 a = *(const float4*)&x[i];
        float4 b = *(const float4*)&x[i + 4];
        *(bf16x8*)&xb[i] = cvt_bf16x8(a, b);
        return;
    }
    const float* w;
    __bf16* wt;
    int K, N, n0, k0;
    if (bx < 4800) {
        int bb = bx - 3072;           // w_attn: 72 n-tiles x 24 k-tiles
        w = wa; wt = wat; K = 768; N = 2304;
        n0 = (bb % 72) * 32; k0 = (bb / 72) * 32;
    } else {
        int bb = bx - 4800;           // w_proj: 24 x 24 tiles
        w = wp; wt = wpt; K = 768; N = 768;
        n0 = (bb % 24) * 32; k0 = (bb / 24) * 32;
    }
    int tx = tid & 31, ty = tid >> 5;
#pragma unroll
    for (int i = 0; i < 4; i++)
        tile[ty + i * 8][tx] = w[(size_t)(k0 + ty + i * 8) * N + n0 + tx];
    __syncthreads();
#pragma unroll
    for (int i = 0; i < 4; i++)
        wt[(size_t)(n0 + ty + i * 8) * K + k0 + tx] = (__bf16)tile[tx][ty + i * 8];
}

// ---------------- QKV GEMM v3 (128x128, BK=64, reg-prefetch pipeline, XCD-swizzled grid) ----------------
// q is pre-scaled by (1/8)*log2(e). 1-D grid of 1152 blocks:
// xcd=bid&7 owns an 8-m-block stripe (A-stripe 1.5MB stays in that XCD's L2).
__global__ __launch_bounds__(256) void qkv_gemm_mfma(const __bf16* __restrict__ A,
                                                     const __bf16* __restrict__ Bt,
                                                     const float* __restrict__ bias,
                                                     __bf16* __restrict__ qb,
                                                     __bf16* __restrict__ kb,
                                                     __bf16* __restrict__ vbt) {
    __shared__ __bf16 smem[128 * 136];           // 34.8KB: staging (32KB) U v-transpose
    __bf16* As = smem;                           // 128*64
    __bf16* Bs = smem + 128 * 64;                // 128*64
    const int tid = threadIdx.x;
    const int wave = tid >> 6, lane = tid & 63;
    const int lane15 = lane & 15, quad = lane >> 4;
    const int bid = blockIdx.x;
    const int m0 = ((bid & 7) * 8 + ((bid >> 3) & 7)) * 128;   // XCD-stripe
    const int n0 = (bid >> 6) * 128;
    const int wm = (wave >> 1) * 64, wn = (wave & 1) * 64;
    f32x4 acc[4][4] = {};

    // per-thread staging chunk coords (4 chunks of 16B for each of A,B)
    int mrow[4], ksrc[4];
#pragma unroll
    for (int r = 0; r < 4; ++r) {
        int p = r * 256 + tid;
        mrow[r] = p >> 3;
        ksrc[r] = ((p & 7) ^ (mrow[r] & 7)) * 8;
    }

    float4 ra[4], rb[4];
#pragma unroll
    for (int r = 0; r < 4; ++r) {
        ra[r] = *(const float4*)(A + (size_t)(m0 + mrow[r]) * 768 + ksrc[r]);
        rb[r] = *(const float4*)(Bt + (size_t)(n0 + mrow[r]) * 768 + ksrc[r]);
    }

    for (int k0 = 0; k0 < 768; k0 += 64) {
        if (k0) __syncthreads();   // previous chunk's readers done
#pragma unroll
        for (int r = 0; r < 4; ++r) {
            int p = r * 256 + tid;
            *(float4*)(As + p * 8) = ra[r];
            *(float4*)(Bs + p * 8) = rb[r];
        }
        if (k0 + 64 < 768) {
            int kn = k0 + 64;
#pragma unroll
            for (int r = 0; r < 4; ++r) {
                ra[r] = *(const float4*)(A + (size_t)(m0 + mrow[r]) * 768 + kn + ksrc[r]);
                rb[r] = *(const float4*)(Bt + (size_t)(n0 + mrow[r]) * 768 + kn + ksrc[r]);
            }
        }
        __syncthreads();           // staging visible
#pragma unroll
        for (int ks = 0; ks < 2; ++ks) {
            bf16x8 af[4], bf[4];
#pragma unroll
            for (int mt = 0; mt < 4; ++mt) {
                int m = wm + mt * 16 + lane15;
                int csw = (ks * 4 + quad) ^ (m & 7);
                af[mt] = *(const bf16x8*)(As + m * 64 + csw * 8);
            }
#pragma unroll
            for (int nt = 0; nt < 4; ++nt) {
                int n = wn + nt * 16 + lane15;
                int csw = (ks * 4 + quad) ^ (n & 7);
                bf[nt] = *(const bf16x8*)(Bs + n * 64 + csw * 8);
            }
#pragma unroll
            for (int mt = 0; mt < 4; ++mt)
#pragma unroll
                for (int nt = 0; nt < 4; ++nt)
                    acc[mt][nt] = __builtin_amdgcn_mfma_f32_16x16x32_bf16(af[mt], bf[nt], acc[mt][nt], 0, 0, 0);
        }
    }
    __syncthreads();   // K-loop LDS reads done before epilogue may reuse smem

    if (n0 < 1536) {
        const bool isq = (n0 < 768);
        const float sc = isq ? (0.125f * LOG2E) : 1.0f;
#pragma unroll
        for (int nt = 0; nt < 4; ++nt) {
            int n = n0 + wn + nt * 16 + lane15;
            int rem = isq ? n : (n - 768);
            int h = rem >> 6;
            int d = n & 63;
            float bv = bias[n];
            __bf16* dst = isq ? qb : kb;
#pragma unroll
            for (int mt = 0; mt < 4; ++mt) {
#pragma unroll
                for (int reg = 0; reg < 4; ++reg) {
                    int mr = m0 + wm + mt * 16 + quad * 4 + reg;
                    int bb = mr >> 10, t = mr & 1023;
                    dst[(((size_t)bb * H_ + h) * T_ + t) * D_ + d] =
                        (__bf16)((acc[mt][nt][reg] + bv) * sc);
                }
            }
        }
    } else {
        // v block: transpose through LDS, coalesced row stores to vbt[bh][d][t]
        __bf16* vls = smem;  // [128 n][136]
#pragma unroll
        for (int nt = 0; nt < 4; ++nt) {
            int nl = wn + nt * 16 + lane15;
            float bv = bias[n0 + nl];
#pragma unroll
            for (int mt = 0; mt < 4; ++mt)
#pragma unroll
                for (int reg = 0; reg < 4; ++reg)
                    vls[nl * 136 + wm + mt * 16 + quad * 4 + reg] =
                        (__bf16)(acc[mt][nt][reg] + bv);
        }
        __syncthreads();
        int nl = tid >> 1;
        int t0 = (tid & 1) * 64;
        int n = n0 + nl;
        int h = (n - 1536) >> 6;
        int d = n & 63;
        int bb = m0 >> 10, tg = (m0 & 1023) + t0;
        __bf16* dst = vbt + (((size_t)bb * H_ + h) * D_ + d) * T_ + tg;
        const __bf16* srcl = vls + nl * 136 + t0;
#pragma unroll
        for (int c = 0; c < 8; ++c)
            *(bf16x8*)(dst + c * 8) = *(const bf16x8*)(srcl + c * 8);
    }
}

// ---------------- proj GEMM v3 (128M x 64N, BK=64, reg-prefetch, XCD-swizzled) ----------------
__global__ __launch_bounds__(256) void proj_gemm_mfma(const __bf16* __restrict__ A,
                                                      const __bf16* __restrict__ Bt,
                                                      const float* __restrict__ bias,
                                                      float* __restrict__ out) {
    __shared__ __bf16 As[128 * 64];
    __shared__ __bf16 Bs[64 * 64];
    const int tid = threadIdx.x;
    const int wave = tid >> 6, lane = tid & 63;
    const int lane15 = lane & 15, quad = lane >> 4;
    const int bid = blockIdx.x;
    const int m0 = ((bid & 7) * 8 + ((bid >> 3) & 7)) * 128;
    const int n0 = (bid >> 6) * 64;
    const int wm = wave * 32;
    f32x4 acc[2][4] = {};

    int mrow[4], ksrc[4];
#pragma unroll
    for (int r = 0; r < 4; ++r) {
        int p = r * 256 + tid;
        mrow[r] = p >> 3;
        ksrc[r] = ((p & 7) ^ (mrow[r] & 7)) * 8;
    }

    float4 ra[4], rb[2];
#pragma unroll
    for (int r = 0; r < 4; ++r)
        ra[r] = *(const float4*)(A + (size_t)(m0 + mrow[r]) * 768 + ksrc[r]);
#pragma unroll
    for (int r = 0; r < 2; ++r)
        rb[r] = *(const float4*)(Bt + (size_t)(n0 + mrow[r]) * 768 + ksrc[r]);

    for (int k0 = 0; k0 < 768; k0 += 64) {
        if (k0) __syncthreads();
#pragma unroll
        for (int r = 0; r < 4; ++r)
            *(float4*)(As + (r * 256 + tid) * 8) = ra[r];
#pragma unroll
        for (int r = 0; r < 2; ++r)
            *(float4*)(Bs + (r * 256 + tid) * 8) = rb[r];
        if (k0 + 64 < 768) {
            int kn = k0 + 64;
#pragma unroll
            for (int r = 0; r < 4; ++r)
                ra[r] = *(const float4*)(A + (size_t)(m0 + mrow[r]) * 768 + kn + ksrc[r]);
#pragma unroll
            for (int r = 0; r < 2; ++r)
                rb[r] = *(const float4*)(Bt + (size_t)(n0 + mrow[r]) * 768 + kn + ksrc[r]);
        }
        __syncthreads();
#pragma unroll
        for (int ks = 0; ks < 2; ++ks) {
            bf16x8 af[2], bf[4];
#pragma unroll
            for (int mt = 0; mt < 2; ++mt) {
                int m = wm + mt * 16 + lane15;
                int csw = (ks * 4 + quad) ^ (m & 7);
                af[mt] = *(const bf16x8*)(As + m * 64 + csw * 8);
            }
#pragma unroll
            for (int nt = 0; nt < 4; ++nt) {
                int n = nt * 16 + lane15;
                int csw = (ks * 4 + quad) ^ (n & 7);
                bf[nt] = *(const bf16x8*)(Bs + n * 64 + csw * 8);
            }
#pragma unroll
            for (int mt = 0; mt < 2; ++mt)
#pragma unroll
                for (int nt = 0; nt < 4; ++nt)
                    acc[mt][nt] = __builtin_amdgcn_mfma_f32_16x16x32_bf16(af[mt], bf[nt], acc[mt][nt], 0, 0, 0);
        }
    }

#pragma unroll
    for (int nt = 0; nt < 4; ++nt) {
        int n = n0 + nt * 16 + lane15;
        float bv = bias[n];
#pragma unroll
        for (int mt = 0; mt < 2; ++mt) {
#pragma unroll
            for (int reg = 0; reg < 4; ++reg) {
                int mr = m0 + wm + mt * 16 + quad * 4 + reg;
                out[(size_t)mr * C_ + n] = acc[mt][nt][reg] + bv;
            }
        }
    }
}

// ---------------- MFMA flash attention v3 (unchanged from R5) ----------------
__global__ __launch_bounds__(256) void attn_mfma(const __bf16* __restrict__ qb,
                                                 const __bf16* __restrict__ kb,
                                                 const __bf16* __restrict__ vbt,
                                                 __bf16* __restrict__ ao) {
    __shared__ __bf16 Ks[2][64 * 64];
    __shared__ __bf16 Vts[2][64 * 64];
    __shared__ __bf16 Ps[4 * 32 * 72];

    const int tid = threadIdx.x;
    const int wave = tid >> 6, lane = tid & 63;
    const int lane15 = lane & 15, quad = lane >> 4;
    const int bh = blockIdx.x;
    const int qt = 7 - blockIdx.y;
    const int b = bh / H_, h = bh % H_;
    const int q0 = qt * 128;

    const __bf16* Kb = kb + (size_t)bh * T_ * D_;
    const __bf16* Vb = vbt + (size_t)bh * D_ * T_;
    __bf16* Pw = Ps + wave * 32 * 72;

    bf16x8 qf[2][2];
#pragma unroll
    for (int g = 0; g < 2; ++g) {
        const __bf16* qrow = qb + ((size_t)bh * T_ + q0 + wave * 32 + g * 16 + lane15) * D_ + quad * 8;
        qf[g][0] = *(const bf16x8*)qrow;
        qf[g][1] = *(const bf16x8*)(qrow + 32);
    }

    f32x4 o[2][4] = {};
    float lsum[2][4] = {};

    const int kunits = 2 * qt + 2;

#define STAGE(KU, BUF)                                                             \
    {                                                                              \
        const int k0s = (KU) * 64;                                                 \
        _Pragma("unroll")                                                          \
        for (int r = 0; r < 2; ++r) {                                              \
            int p = r * 256 + tid;                                                 \
            int row = p >> 3, c = p & 7;                                           \
            int cs = (c ^ (row & 7)) * 8;                                          \
            __builtin_amdgcn_global_load_lds(                                      \
                (gptr_t)(Kb + (size_t)(k0s + row) * D_ + cs),                      \
                (lptr_t)(&Ks[BUF][0] + (r * 256 + wave * 64) * 8), 16, 0, 0);      \
            __builtin_amdgcn_global_load_lds(                                      \
                (gptr_t)(Vb + (size_t)row * T_ + k0s + cs),                        \
                (lptr_t)(&Vts[BUF][0] + (r * 256 + wave * 64) * 8), 16, 0, 0);     \
        }                                                                          \
    }

    STAGE(0, 0);

    for (int ku = 0; ku < kunits; ++ku) {
        __syncthreads();
        if (ku + 1 < kunits) STAGE(ku + 1, (ku + 1) & 1);
        const __bf16* Kc = &Ks[ku & 1][0];
        const __bf16* Vc = &Vts[ku & 1][0];
        const int k0 = ku * 64;

        f32x4 s[2][4];
#pragma unroll
        for (int kt = 0; kt < 4; ++kt) {
            int row = kt * 16 + lane15;
            bf16x8 kf0 = *(const bf16x8*)(Kc + row * 64 + ((quad) ^ (row & 7)) * 8);
            bf16x8 kf1 = *(const bf16x8*)(Kc + row * 64 + ((4 + quad) ^ (row & 7)) * 8);
#pragma unroll
            for (int g = 0; g < 2; ++g) {
                f32x4 t = {};
                t = __builtin_amdgcn_mfma_f32_16x16x32_bf16(qf[g][0], kf0, t, 0, 0, 0);
                t = __builtin_amdgcn_mfma_f32_16x16x32_bf16(qf[g][1], kf1, t, 0, 0, 0);
                s[g][kt] = t;
            }
        }

        const bool diag = (ku >= 2 * qt);
#pragma unroll
        for (int g = 0; g < 2; ++g) {
#pragma unroll
            for (int kt = 0; kt < 4; ++kt) {
                int col = k0 + kt * 16 + lane15;
#pragma unroll
                for (int r = 0; r < 4; ++r) {
                    float p = __builtin_amdgcn_exp2f(s[g][kt][r]);
                    if (diag) {
                        int qrow = q0 + wave * 32 + g * 16 + quad * 4 + r;
                        if (col > qrow) p = 0.f;
                    }
                    lsum[g][r] += p;
                    Pw[(g * 16 + quad * 4 + r) * 72 + kt * 16 + lane15] = (__bf16)p;
                }
            }
        }

        bf16x8 vf[4][2];
#pragma unroll
        for (int dt = 0; dt < 4; ++dt) {
            int row = dt * 16 + lane15;
#pragma unroll
            for (int half = 0; half < 2; ++half)
                vf[dt][half] = *(const bf16x8*)(Vc + row * 64 + ((half * 4 + quad) ^ (row & 7)) * 8);
        }
#pragma unroll
        for (int g = 0; g < 2; ++g) {
#pragma unroll
            for (int half = 0; half < 2; ++half) {
                bf16x8 pf = *(const bf16x8*)(Pw + (g * 16 + lane15) * 72 + half * 32 + quad * 8);
#pragma unroll
                for (int dt = 0; dt < 4; ++dt)
                    o[g][dt] = __builtin_amdgcn_mfma_f32_16x16x32_bf16(pf, vf[dt][half], o[g][dt], 0, 0, 0);
            }
        }
    }

#pragma unroll
    for (int g = 0; g < 2; ++g) {
        float inv[4];
#pragma unroll
        for (int r = 0; r < 4; ++r) {
            float ls = lsum[g][r];
            ls += __shfl_xor(ls, 1);
            ls += __shfl_xor(ls, 2);
            ls += __shfl_xor(ls, 4);
            ls += __shfl_xor(ls, 8);
            inv[r] = 1.0f / ls;
        }
#pragma unroll
        for (int dt = 0; dt < 4; ++dt) {
#pragma unroll
            for (int r = 0; r < 4; ++r) {
                int t = q0 + wave * 32 + g * 16 + quad * 4 + r;
                ao[((size_t)(b * T_ + t)) * C_ + h * 64 + dt * 16 + lane15] =
                    (__bf16)(o[g][dt][r] * inv[r]);
            }
        }
    }
}

extern "C" void kernel_launch(void* const* d_in, const int* in_sizes, int n_in,
                              void* d_out, int out_size, void* d_ws, size_t ws_size,
                              hipStream_t stream) {
    const float* x = (const float*)d_in[0];
    const float* w_attn = (const float*)d_in[1];
    const float* b_attn = (const float*)d_in[2];
    const float* w_proj = (const float*)d_in[3];
    const float* b_proj = (const float*)d_in[4];
    float* out = (float*)d_out;

    __bf16* xb = (__bf16*)d_ws;
    __bf16* wat = xb + (size_t)M_ * C_;
    __bf16* wpt = wat + (size_t)N3C * C_;
    __bf16* qb = wpt + (size_t)C_ * C_;         // pre-scaled by (1/8)log2e
    __bf16* kb = qb + (size_t)96 * T_ * D_;
    __bf16* vbt = kb + (size_t)96 * T_ * D_;    // [96][64][1024]
    __bf16* ao = vbt + (size_t)96 * T_ * D_;

    prepass<<<5376, 256, 0, stream>>>(x, xb, w_attn, wat, w_proj, wpt);
    qkv_gemm_mfma<<<1152, 256, 0, stream>>>(xb, wat, b_attn, qb, kb, vbt);
    attn_mfma<<<dim3(96, 8), 256, 0, stream>>>(qb, kb, vbt, ao);
    proj_gemm_mfma<<<768, 256, 0, stream>>>(ao, wpt, b_proj, out);
}

// Round 7
// 188.873 us; speedup vs baseline: 1.6313x; 1.6313x over previous
//
#include <hip/hip_runtime.h>
#include <hip/hip_bf16.h>
#include <cmath>

// B=8, T=1024, C=768, H=12, D=64
#define B_ 8
#define T_ 1024
#define C_ 768
#define H_ 12
#define D_ 64
#define N3C 2304
#define M_ 8192   // B*T

typedef __bf16 bf16x8 __attribute__((ext_vector_type(8)));
typedef float  f32x4  __attribute__((ext_vector_type(4)));

typedef const __attribute__((address_space(1))) void* gptr_t;
typedef __attribute__((address_space(3))) void* lptr_t;

#define LOG2E 1.44269504088896f

__device__ __forceinline__ bf16x8 cvt_bf16x8(const float4& a, const float4& b) {
    bf16x8 r;
    r[0] = (__bf16)a.x; r[1] = (__bf16)a.y; r[2] = (__bf16)a.z; r[3] = (__bf16)a.w;
    r[4] = (__bf16)b.x; r[5] = (__bf16)b.y; r[6] = (__bf16)b.z; r[7] = (__bf16)b.w;
    return r;
}

// ---------------- fused pre-pass: cast x + transpose-cast both weights ----------------
__global__ __launch_bounds__(256) void prepass(const float* __restrict__ x,
                                               __bf16* __restrict__ xb,
                                               const float* __restrict__ wa,
                                               __bf16* __restrict__ wat,
                                               const float* __restrict__ wp,
                                               __bf16* __restrict__ wpt) {
    __shared__ float tile[32][33];
    const int bx = blockIdx.x, tid = threadIdx.x;
    if (bx < 3072) {
        int i = (bx * 256 + tid) * 8;
        float4 a = *(const float4*)&x[i];
        float4 b = *(const float4*)&x[i + 4];
        *(bf16x8*)&xb[i] = cvt_bf16x8(a, b);
        return;
    }
    const float* w;
    __bf16* wt;
    int K, N, n0, k0;
    if (bx < 4800) {
        int bb = bx - 3072;           // w_attn: 72 n-tiles x 24 k-tiles
        w = wa; wt = wat; K = 768; N = 2304;
        n0 = (bb % 72) * 32; k0 = (bb / 72) * 32;
    } else {
        int bb = bx - 4800;           // w_proj: 24 x 24 tiles
        w = wp; wt = wpt; K = 768; N = 768;
        n0 = (bb % 24) * 32; k0 = (bb / 24) * 32;
    }
    int tx = tid & 31, ty = tid >> 5;
#pragma unroll
    for (int i = 0; i < 4; i++)
        tile[ty + i * 8][tx] = w[(size_t)(k0 + ty + i * 8) * N + n0 + tx];
    __syncthreads();
#pragma unroll
    for (int i = 0; i < 4; i++)
        wt[(size_t)(n0 + ty + i * 8) * K + k0 + tx] = (__bf16)tile[tx][ty + i * 8];
}

// ---------------- QKV GEMM (128x128, BK=64, global_load_lds staging, XCD-swizzled grid) ----------------
// q is pre-scaled by (1/8)*log2(e). 1-D grid 1152: xcd=bid&7 owns an 8-m-tile
// stripe (A-stripe 1.5MB resident in that XCD's L2 -> vmcnt drain hits L2 not HBM).
__global__ __launch_bounds__(256) void qkv_gemm_mfma(const __bf16* __restrict__ A,
                                                     const __bf16* __restrict__ Bt,
                                                     const float* __restrict__ bias,
                                                     __bf16* __restrict__ qb,
                                                     __bf16* __restrict__ kb,
                                                     __bf16* __restrict__ vbt) {
    __shared__ __bf16 smem[128 * 136];           // staging (32KB) U v-transpose
    __bf16* As = smem;                           // 128*64
    __bf16* Bs = smem + 128 * 64;                // 128*64
    const int tid = threadIdx.x;
    const int wave = tid >> 6, lane = tid & 63;
    const int lane15 = lane & 15, quad = lane >> 4;
    const int bid = blockIdx.x;
    const int m0 = ((bid & 7) * 8 + ((bid >> 3) & 7)) * 128;   // XCD-stripe
    const int n0 = (bid >> 6) * 128;
    const int wm = (wave >> 1) * 64, wn = (wave & 1) * 64;
    f32x4 acc[4][4] = {};

    for (int k0 = 0; k0 < 768; k0 += 64) {
#pragma unroll
        for (int r = 0; r < 4; ++r) {
            int p = r * 256 + tid;
            int mrow = p >> 3, csw = p & 7;
            int ksrc = (csw ^ (mrow & 7)) * 8;
            __builtin_amdgcn_global_load_lds(
                (gptr_t)(A + (size_t)(m0 + mrow) * 768 + k0 + ksrc),
                (lptr_t)(As + (r * 256 + wave * 64) * 8), 16, 0, 0);
            __builtin_amdgcn_global_load_lds(
                (gptr_t)(Bt + (size_t)(n0 + mrow) * 768 + k0 + ksrc),
                (lptr_t)(Bs + (r * 256 + wave * 64) * 8), 16, 0, 0);
        }
        __syncthreads();
#pragma unroll
        for (int ks = 0; ks < 2; ++ks) {
            bf16x8 af[4], bf[4];
#pragma unroll
            for (int mt = 0; mt < 4; ++mt) {
                int m = wm + mt * 16 + lane15;
                int csw = (ks * 4 + quad) ^ (m & 7);
                af[mt] = *(const bf16x8*)(As + m * 64 + csw * 8);
            }
#pragma unroll
            for (int nt = 0; nt < 4; ++nt) {
                int n = wn + nt * 16 + lane15;
                int csw = (ks * 4 + quad) ^ (n & 7);
                bf[nt] = *(const bf16x8*)(Bs + n * 64 + csw * 8);
            }
#pragma unroll
            for (int mt = 0; mt < 4; ++mt)
#pragma unroll
                for (int nt = 0; nt < 4; ++nt)
                    acc[mt][nt] = __builtin_amdgcn_mfma_f32_16x16x32_bf16(af[mt], bf[nt], acc[mt][nt], 0, 0, 0);
        }
        __syncthreads();
    }

    if (n0 < 1536) {
        const bool isq = (n0 < 768);
        const float sc = isq ? (0.125f * LOG2E) : 1.0f;
#pragma unroll
        for (int nt = 0; nt < 4; ++nt) {
            int n = n0 + wn + nt * 16 + lane15;
            int rem = isq ? n : (n - 768);
            int h = rem >> 6;
            int d = n & 63;
            float bv = bias[n];
            __bf16* dst = isq ? qb : kb;
#pragma unroll
            for (int mt = 0; mt < 4; ++mt) {
#pragma unroll
                for (int reg = 0; reg < 4; ++reg) {
                    int mr = m0 + wm + mt * 16 + quad * 4 + reg;
                    int bb = mr >> 10, t = mr & 1023;
                    dst[(((size_t)bb * H_ + h) * T_ + t) * D_ + d] =
                        (__bf16)((acc[mt][nt][reg] + bv) * sc);
                }
            }
        }
    } else {
        // v block: transpose through LDS, coalesced row stores to vbt[bh][d][t]
        __bf16* vls = smem;  // [128 n][136]
#pragma unroll
        for (int nt = 0; nt < 4; ++nt) {
            int nl = wn + nt * 16 + lane15;
            float bv = bias[n0 + nl];
#pragma unroll
            for (int mt = 0; mt < 4; ++mt)
#pragma unroll
                for (int reg = 0; reg < 4; ++reg)
                    vls[nl * 136 + wm + mt * 16 + quad * 4 + reg] =
                        (__bf16)(acc[mt][nt][reg] + bv);
        }
        __syncthreads();
        int nl = tid >> 1;
        int t0 = (tid & 1) * 64;
        int n = n0 + nl;
        int h = (n - 1536) >> 6;
        int d = n & 63;
        int bb = m0 >> 10, tg = (m0 & 1023) + t0;
        __bf16* dst = vbt + (((size_t)bb * H_ + h) * D_ + d) * T_ + tg;
        const __bf16* srcl = vls + nl * 136 + t0;
#pragma unroll
        for (int c = 0; c < 8; ++c)
            *(bf16x8*)(dst + c * 8) = *(const bf16x8*)(srcl + c * 8);
    }
}

// ---------------- proj GEMM (128M x 64N, BK=64, global_load_lds, XCD-swizzled) ----------------
__global__ __launch_bounds__(256) void proj_gemm_mfma(const __bf16* __restrict__ A,
                                                      const __bf16* __restrict__ Bt,
                                                      const float* __restrict__ bias,
                                                      float* __restrict__ out) {
    __shared__ __bf16 As[128 * 64];
    __shared__ __bf16 Bs[64 * 64];
    const int tid = threadIdx.x;
    const int wave = tid >> 6, lane = tid & 63;
    const int lane15 = lane & 15, quad = lane >> 4;
    const int bid = blockIdx.x;
    const int m0 = ((bid & 7) * 8 + ((bid >> 3) & 7)) * 128;
    const int n0 = (bid >> 6) * 64;
    const int wm = wave * 32;
    f32x4 acc[2][4] = {};

    for (int k0 = 0; k0 < 768; k0 += 64) {
#pragma unroll
        for (int r = 0; r < 4; ++r) {
            int p = r * 256 + tid;
            int mrow = p >> 3, csw = p & 7;
            int ksrc = (csw ^ (mrow & 7)) * 8;
            __builtin_amdgcn_global_load_lds(
                (gptr_t)(A + (size_t)(m0 + mrow) * 768 + k0 + ksrc),
                (lptr_t)(As + (r * 256 + wave * 64) * 8), 16, 0, 0);
        }
#pragma unroll
        for (int r = 0; r < 2; ++r) {
            int p = r * 256 + tid;
            int nrow = p >> 3, csw = p & 7;
            int ksrc = (csw ^ (nrow & 7)) * 8;
            __builtin_amdgcn_global_load_lds(
                (gptr_t)(Bt + (size_t)(n0 + nrow) * 768 + k0 + ksrc),
                (lptr_t)(Bs + (r * 256 + wave * 64) * 8), 16, 0, 0);
        }
        __syncthreads();
#pragma unroll
        for (int ks = 0; ks < 2; ++ks) {
            bf16x8 af[2], bf[4];
#pragma unroll
            for (int mt = 0; mt < 2; ++mt) {
                int m = wm + mt * 16 + lane15;
                int csw = (ks * 4 + quad) ^ (m & 7);
                af[mt] = *(const bf16x8*)(As + m * 64 + csw * 8);
            }
#pragma unroll
            for (int nt = 0; nt < 4; ++nt) {
                int n = nt * 16 + lane15;
                int csw = (ks * 4 + quad) ^ (n & 7);
                bf[nt] = *(const bf16x8*)(Bs + n * 64 + csw * 8);
            }
#pragma unroll
            for (int mt = 0; mt < 2; ++mt)
#pragma unroll
                for (int nt = 0; nt < 4; ++nt)
                    acc[mt][nt] = __builtin_amdgcn_mfma_f32_16x16x32_bf16(af[mt], bf[nt], acc[mt][nt], 0, 0, 0);
        }
        __syncthreads();
    }

#pragma unroll
    for (int nt = 0; nt < 4; ++nt) {
        int n = n0 + nt * 16 + lane15;
        float bv = bias[n];
#pragma unroll
        for (int mt = 0; mt < 2; ++mt) {
#pragma unroll
            for (int reg = 0; reg < 4; ++reg) {
                int mr = m0 + wm + mt * 16 + quad * 4 + reg;
                out[(size_t)mr * C_ + n] = acc[mt][nt][reg] + bv;
            }
        }
    }
}

// ---------------- MFMA flash attention v3 (unchanged from R5) ----------------
__global__ __launch_bounds__(256) void attn_mfma(const __bf16* __restrict__ qb,
                                                 const __bf16* __restrict__ kb,
                                                 const __bf16* __restrict__ vbt,
                                                 __bf16* __restrict__ ao) {
    __shared__ __bf16 Ks[2][64 * 64];
    __shared__ __bf16 Vts[2][64 * 64];
    __shared__ __bf16 Ps[4 * 32 * 72];

    const int tid = threadIdx.x;
    const int wave = tid >> 6, lane = tid & 63;
    const int lane15 = lane & 15, quad = lane >> 4;
    const int bh = blockIdx.x;
    const int qt = 7 - blockIdx.y;
    const int b = bh / H_, h = bh % H_;
    const int q0 = qt * 128;

    const __bf16* Kb = kb + (size_t)bh * T_ * D_;
    const __bf16* Vb = vbt + (size_t)bh * D_ * T_;
    __bf16* Pw = Ps + wave * 32 * 72;

    bf16x8 qf[2][2];
#pragma unroll
    for (int g = 0; g < 2; ++g) {
        const __bf16* qrow = qb + ((size_t)bh * T_ + q0 + wave * 32 + g * 16 + lane15) * D_ + quad * 8;
        qf[g][0] = *(const bf16x8*)qrow;
        qf[g][1] = *(const bf16x8*)(qrow + 32);
    }

    f32x4 o[2][4] = {};
    float lsum[2][4] = {};

    const int kunits = 2 * qt + 2;

#define STAGE(KU, BUF)                                                             \
    {                                                                              \
        const int k0s = (KU) * 64;                                                 \
        _Pragma("unroll")                                                          \
        for (int r = 0; r < 2; ++r) {                                              \
            int p = r * 256 + tid;                                                 \
            int row = p >> 3, c = p & 7;                                           \
            int cs = (c ^ (row & 7)) * 8;                                          \
            __builtin_amdgcn_global_load_lds(                                      \
                (gptr_t)(Kb + (size_t)(k0s + row) * D_ + cs),                      \
                (lptr_t)(&Ks[BUF][0] + (r * 256 + wave * 64) * 8), 16, 0, 0);      \
            __builtin_amdgcn_global_load_lds(                                      \
                (gptr_t)(Vb + (size_t)row * T_ + k0s + cs),                        \
                (lptr_t)(&Vts[BUF][0] + (r * 256 + wave * 64) * 8), 16, 0, 0);     \
        }                                                                          \
    }

    STAGE(0, 0);

    for (int ku = 0; ku < kunits; ++ku) {
        __syncthreads();
        if (ku + 1 < kunits) STAGE(ku + 1, (ku + 1) & 1);
        const __bf16* Kc = &Ks[ku & 1][0];
        const __bf16* Vc = &Vts[ku & 1][0];
        const int k0 = ku * 64;

        f32x4 s[2][4];
#pragma unroll
        for (int kt = 0; kt < 4; ++kt) {
            int row = kt * 16 + lane15;
            bf16x8 kf0 = *(const bf16x8*)(Kc + row * 64 + ((quad) ^ (row & 7)) * 8);
            bf16x8 kf1 = *(const bf16x8*)(Kc + row * 64 + ((4 + quad) ^ (row & 7)) * 8);
#pragma unroll
            for (int g = 0; g < 2; ++g) {
                f32x4 t = {};
                t = __builtin_amdgcn_mfma_f32_16x16x32_bf16(qf[g][0], kf0, t, 0, 0, 0);
                t = __builtin_amdgcn_mfma_f32_16x16x32_bf16(qf[g][1], kf1, t, 0, 0, 0);
                s[g][kt] = t;
            }
        }

        const bool diag = (ku >= 2 * qt);
#pragma unroll
        for (int g = 0; g < 2; ++g) {
#pragma unroll
            for (int kt = 0; kt < 4; ++kt) {
                int col = k0 + kt * 16 + lane15;
#pragma unroll
                for (int r = 0; r < 4; ++r) {
                    float p = __builtin_amdgcn_exp2f(s[g][kt][r]);
                    if (diag) {
                        int qrow = q0 + wave * 32 + g * 16 + quad * 4 + r;
                        if (col > qrow) p = 0.f;
                    }
                    lsum[g][r] += p;
                    Pw[(g * 16 + quad * 4 + r) * 72 + kt * 16 + lane15] = (__bf16)p;
                }
            }
        }

        bf16x8 vf[4][2];
#pragma unroll
        for (int dt = 0; dt < 4; ++dt) {
            int row = dt * 16 + lane15;
#pragma unroll
            for (int half = 0; half < 2; ++half)
                vf[dt][half] = *(const bf16x8*)(Vc + row * 64 + ((half * 4 + quad) ^ (row & 7)) * 8);
        }
#pragma unroll
        for (int g = 0; g < 2; ++g) {
#pragma unroll
            for (int half = 0; half < 2; ++half) {
                bf16x8 pf = *(const bf16x8*)(Pw + (g * 16 + lane15) * 72 + half * 32 + quad * 8);
#pragma unroll
                for (int dt = 0; dt < 4; ++dt)
                    o[g][dt] = __builtin_amdgcn_mfma_f32_16x16x32_bf16(pf, vf[dt][half], o[g][dt], 0, 0, 0);
            }
        }
    }

#pragma unroll
    for (int g = 0; g < 2; ++g) {
        float inv[4];
#pragma unroll
        for (int r = 0; r < 4; ++r) {
            float ls = lsum[g][r];
            ls += __shfl_xor(ls, 1);
            ls += __shfl_xor(ls, 2);
            ls += __shfl_xor(ls, 4);
            ls += __shfl_xor(ls, 8);
            inv[r] = 1.0f / ls;
        }
#pragma unroll
        for (int dt = 0; dt < 4; ++dt) {
#pragma unroll
            for (int r = 0; r < 4; ++r) {
                int t = q0 + wave * 32 + g * 16 + quad * 4 + r;
                ao[((size_t)(b * T_ + t)) * C_ + h * 64 + dt * 16 + lane15] =
                    (__bf16)(o[g][dt][r] * inv[r]);
            }
        }
    }
}

extern "C" void kernel_launch(void* const* d_in, const int* in_sizes, int n_in,
                              void* d_out, int out_size, void* d_ws, size_t ws_size,
                              hipStream_t stream) {
    const float* x = (const float*)d_in[0];
    const float* w_attn = (const float*)d_in[1];
    const float* b_attn = (const float*)d_in[2];
    const float* w_proj = (const float*)d_in[3];
    const float* b_proj = (const float*)d_in[4];
    float* out = (float*)d_out;

    __bf16* xb = (__bf16*)d_ws;
    __bf16* wat = xb + (size_t)M_ * C_;
    __bf16* wpt = wat + (size_t)N3C * C_;
    __bf16* qb = wpt + (size_t)C_ * C_;         // pre-scaled by (1/8)log2e
    __bf16* kb = qb + (size_t)96 * T_ * D_;
    __bf16* vbt = kb + (size_t)96 * T_ * D_;    // [96][64][1024]
    __bf16* ao = vbt + (size_t)96 * T_ * D_;

    prepass<<<5376, 256, 0, stream>>>(x, xb, w_attn, wat, w_proj, wpt);
    qkv_gemm_mfma<<<1152, 256, 0, stream>>>(xb, wat, b_attn, qb, kb, vbt);
    attn_mfma<<<dim3(96, 8), 256, 0, stream>>>(qb, kb, vbt, ao);
    proj_gemm_mfma<<<768, 256, 0, stream>>>(ao, wpt, b_proj, out);
}

// Round 8
// 175.926 us; speedup vs baseline: 1.7514x; 1.0736x over previous
//
#include <hip/hip_runtime.h>
#include <hip/hip_bf16.h>
#include <cmath>

// B=8, T=1024, C=768, H=12, D=64
#define B_ 8
#define T_ 1024
#define C_ 768
#define H_ 12
#define D_ 64
#define N3C 2304
#define M_ 8192   // B*T

typedef __bf16 bf16x4 __attribute__((ext_vector_type(4)));
typedef __bf16 bf16x8 __attribute__((ext_vector_type(8)));
typedef float  f32x4  __attribute__((ext_vector_type(4)));

typedef const __attribute__((address_space(1))) void* gptr_t;
typedef __attribute__((address_space(3))) void* lptr_t;

#define LOG2E 1.44269504088896f

__device__ __forceinline__ bf16x8 cvt_bf16x8(const float4& a, const float4& b) {
    bf16x8 r;
    r[0] = (__bf16)a.x; r[1] = (__bf16)a.y; r[2] = (__bf16)a.z; r[3] = (__bf16)a.w;
    r[4] = (__bf16)b.x; r[5] = (__bf16)b.y; r[6] = (__bf16)b.z; r[7] = (__bf16)b.w;
    return r;
}

// ---------------- fused pre-pass: cast x + transpose-cast both weights ----------------
__global__ __launch_bounds__(256) void prepass(const float* __restrict__ x,
                                               __bf16* __restrict__ xb,
                                               const float* __restrict__ wa,
                                               __bf16* __restrict__ wat,
                                               const float* __restrict__ wp,
                                               __bf16* __restrict__ wpt) {
    __shared__ float tile[32][33];
    const int bx = blockIdx.x, tid = threadIdx.x;
    if (bx < 3072) {
        int i = (bx * 256 + tid) * 8;
        float4 a = *(const float4*)&x[i];
        float4 b = *(const float4*)&x[i + 4];
        *(bf16x8*)&xb[i] = cvt_bf16x8(a, b);
        return;
    }
    const float* w;
    __bf16* wt;
    int K, N, n0, k0;
    if (bx < 4800) {
        int bb = bx - 3072;           // w_attn: 72 n-tiles x 24 k-tiles
        w = wa; wt = wat; K = 768; N = 2304;
        n0 = (bb % 72) * 32; k0 = (bb / 72) * 32;
    } else {
        int bb = bx - 4800;           // w_proj: 24 x 24 tiles
        w = wp; wt = wpt; K = 768; N = 768;
        n0 = (bb % 24) * 32; k0 = (bb / 24) * 32;
    }
    int tx = tid & 31, ty = tid >> 5;
#pragma unroll
    for (int i = 0; i < 4; i++)
        tile[ty + i * 8][tx] = w[(size_t)(k0 + ty + i * 8) * N + n0 + tx];
    __syncthreads();
#pragma unroll
    for (int i = 0; i < 4; i++)
        wt[(size_t)(n0 + ty + i * 8) * K + k0 + tx] = (__bf16)tile[tx][ty + i * 8];
}

// ---------------- QKV GEMM v4: 128x128, BK=64, LDS double-buffer (1 barrier/iter), XCD grid ----------------
// q pre-scaled by (1/8)*log2(e). V stored to vbt[bh][d][.] with the within-64-key
// permutation s = (k%16)*4 + k/16 baked into the column order (attn's P/V layout match).
__global__ __launch_bounds__(256) void qkv_gemm_mfma(const __bf16* __restrict__ A,
                                                     const __bf16* __restrict__ Bt,
                                                     const float* __restrict__ bias,
                                                     __bf16* __restrict__ qb,
                                                     __bf16* __restrict__ kb,
                                                     __bf16* __restrict__ vbt) {
    __shared__ __bf16 smem[2][2][128 * 64];      // 64KB: [buf][A/B][tile]; epilogue reuses
    const int tid = threadIdx.x;
    const int wave = tid >> 6, lane = tid & 63;
    const int lane15 = lane & 15, quad = lane >> 4;
    const int bid = blockIdx.x;
    const int m0 = ((bid & 7) * 8 + ((bid >> 3) & 7)) * 128;   // XCD-stripe
    const int n0 = (bid >> 6) * 128;
    const int wm = (wave >> 1) * 64, wn = (wave & 1) * 64;
    f32x4 acc[4][4] = {};

#define QSTAGE(KC, BUF)                                                             \
    {                                                                               \
        const int k0s = (KC) * 64;                                                  \
        _Pragma("unroll")                                                           \
        for (int r = 0; r < 4; ++r) {                                               \
            int p = r * 256 + tid;                                                  \
            int mrow = p >> 3, csw = p & 7;                                         \
            int ksrc = (csw ^ (mrow & 7)) * 8;                                      \
            __builtin_amdgcn_global_load_lds(                                       \
                (gptr_t)(A + (size_t)(m0 + mrow) * 768 + k0s + ksrc),               \
                (lptr_t)(&smem[BUF][0][0] + (r * 256 + wave * 64) * 8), 16, 0, 0);  \
            __builtin_amdgcn_global_load_lds(                                       \
                (gptr_t)(Bt + (size_t)(n0 + mrow) * 768 + k0s + ksrc),              \
                (lptr_t)(&smem[BUF][1][0] + (r * 256 + wave * 64) * 8), 16, 0, 0);  \
        }                                                                           \
    }

    QSTAGE(0, 0);
    for (int kc = 0; kc < 12; ++kc) {
        __syncthreads();                       // drains stage(kc) (issued prev iter)
        if (kc + 1 < 12) QSTAGE(kc + 1, (kc + 1) & 1);
        const __bf16* As = &smem[kc & 1][0][0];
        const __bf16* Bs = &smem[kc & 1][1][0];
#pragma unroll
        for (int ks = 0; ks < 2; ++ks) {
            bf16x8 af[4], bf[4];
#pragma unroll
            for (int mt = 0; mt < 4; ++mt) {
                int m = wm + mt * 16 + lane15;
                int csw = (ks * 4 + quad) ^ (m & 7);
                af[mt] = *(const bf16x8*)(As + m * 64 + csw * 8);
            }
#pragma unroll
            for (int nt = 0; nt < 4; ++nt) {
                int n = wn + nt * 16 + lane15;
                int csw = (ks * 4 + quad) ^ (n & 7);
                bf[nt] = *(const bf16x8*)(Bs + n * 64 + csw * 8);
            }
#pragma unroll
            for (int mt = 0; mt < 4; ++mt)
#pragma unroll
                for (int nt = 0; nt < 4; ++nt)
                    acc[mt][nt] = __builtin_amdgcn_mfma_f32_16x16x32_bf16(af[mt], bf[nt], acc[mt][nt], 0, 0, 0);
        }
    }
    __syncthreads();   // all LDS reads done before epilogue reuses smem

    if (n0 < 1536) {
        const bool isq = (n0 < 768);
        const float sc = isq ? (0.125f * LOG2E) : 1.0f;
#pragma unroll
        for (int nt = 0; nt < 4; ++nt) {
            int n = n0 + wn + nt * 16 + lane15;
            int rem = isq ? n : (n - 768);
            int h = rem >> 6;
            int d = n & 63;
            float bv = bias[n];
            __bf16* dst = isq ? qb : kb;
#pragma unroll
            for (int mt = 0; mt < 4; ++mt) {
#pragma unroll
                for (int reg = 0; reg < 4; ++reg) {
                    int mr = m0 + wm + mt * 16 + quad * 4 + reg;
                    int bb = mr >> 10, t = mr & 1023;
                    dst[(((size_t)bb * H_ + h) * T_ + t) * D_ + d] =
                        (__bf16)((acc[mt][nt][reg] + bv) * sc);
                }
            }
        }
    } else {
        // v block: transpose through LDS; store with within-64-key permutation
        // storage position s (0..63) holds key t_local = (s&3)*16 + (s>>2)
        __bf16* vls = &smem[0][0][0];  // [128 n][136]
#pragma unroll
        for (int nt = 0; nt < 4; ++nt) {
            int nl = wn + nt * 16 + lane15;
            float bv = bias[n0 + nl];
#pragma unroll
            for (int mt = 0; mt < 4; ++mt)
#pragma unroll
                for (int reg = 0; reg < 4; ++reg)
                    vls[nl * 136 + wm + mt * 16 + quad * 4 + reg] =
                        (__bf16)(acc[mt][nt][reg] + bv);
        }
        __syncthreads();
        int nl = tid >> 1;
        int t0 = (tid & 1) * 64;
        int n = n0 + nl;
        int h = (n - 1536) >> 6;
        int d = n & 63;
        int bb = m0 >> 10, tg = (m0 & 1023) + t0;
        __bf16* dst = vbt + (((size_t)bb * H_ + h) * D_ + d) * T_ + tg;
        const __bf16* srcl = vls + nl * 136 + t0;
#pragma unroll
        for (int c = 0; c < 8; ++c) {
            bf16x8 v;
#pragma unroll
            for (int i = 0; i < 8; ++i) {
                int s = c * 8 + i;
                v[i] = srcl[(s & 3) * 16 + (s >> 2)];
            }
            *(bf16x8*)(dst + c * 8) = v;
        }
    }
}

// ---------------- proj GEMM v4: 128M x 64N, BK=64, LDS double-buffer, XCD grid ----------------
__global__ __launch_bounds__(256) void proj_gemm_mfma(const __bf16* __restrict__ A,
                                                      const __bf16* __restrict__ Bt,
                                                      const float* __restrict__ bias,
                                                      float* __restrict__ out) {
    __shared__ __bf16 As[2][128 * 64];
    __shared__ __bf16 Bs[2][64 * 64];
    const int tid = threadIdx.x;
    const int wave = tid >> 6, lane = tid & 63;
    const int lane15 = lane & 15, quad = lane >> 4;
    const int bid = blockIdx.x;
    const int m0 = ((bid & 7) * 8 + ((bid >> 3) & 7)) * 128;
    const int n0 = (bid >> 6) * 64;
    const int wm = wave * 32;
    f32x4 acc[2][4] = {};

#define PSTAGE(KC, BUF)                                                             \
    {                                                                               \
        const int k0s = (KC) * 64;                                                  \
        _Pragma("unroll")                                                           \
        for (int r = 0; r < 4; ++r) {                                               \
            int p = r * 256 + tid;                                                  \
            int mrow = p >> 3, csw = p & 7;                                         \
            int ksrc = (csw ^ (mrow & 7)) * 8;                                      \
            __builtin_amdgcn_global_load_lds(                                       \
                (gptr_t)(A + (size_t)(m0 + mrow) * 768 + k0s + ksrc),               \
                (lptr_t)(&As[BUF][0] + (r * 256 + wave * 64) * 8), 16, 0, 0);       \
        }                                                                           \
        _Pragma("unroll")                                                           \
        for (int r = 0; r < 2; ++r) {                                               \
            int p = r * 256 + tid;                                                  \
            int nrow = p >> 3, csw = p & 7;                                         \
            int ksrc = (csw ^ (nrow & 7)) * 8;                                      \
            __builtin_amdgcn_global_load_lds(                                       \
                (gptr_t)(Bt + (size_t)(n0 + nrow) * 768 + k0s + ksrc),              \
                (lptr_t)(&Bs[BUF][0] + (r * 256 + wave * 64) * 8), 16, 0, 0);       \
        }                                                                           \
    }

    PSTAGE(0, 0);
    for (int kc = 0; kc < 12; ++kc) {
        __syncthreads();
        if (kc + 1 < 12) PSTAGE(kc + 1, (kc + 1) & 1);
        const __bf16* Ac = &As[kc & 1][0];
        const __bf16* Bc = &Bs[kc & 1][0];
#pragma unroll
        for (int ks = 0; ks < 2; ++ks) {
            bf16x8 af[2], bf[4];
#pragma unroll
            for (int mt = 0; mt < 2; ++mt) {
                int m = wm + mt * 16 + lane15;
                int csw = (ks * 4 + quad) ^ (m & 7);
                af[mt] = *(const bf16x8*)(Ac + m * 64 + csw * 8);
            }
#pragma unroll
            for (int nt = 0; nt < 4; ++nt) {
                int n = nt * 16 + lane15;
                int csw = (ks * 4 + quad) ^ (n & 7);
                bf[nt] = *(const bf16x8*)(Bc + n * 64 + csw * 8);
            }
#pragma unroll
            for (int mt = 0; mt < 2; ++mt)
#pragma unroll
                for (int nt = 0; nt < 4; ++nt)
                    acc[mt][nt] = __builtin_amdgcn_mfma_f32_16x16x32_bf16(af[mt], bf[nt], acc[mt][nt], 0, 0, 0);
        }
    }

#pragma unroll
    for (int nt = 0; nt < 4; ++nt) {
        int n = n0 + nt * 16 + lane15;
        float bv = bias[n];
#pragma unroll
        for (int mt = 0; mt < 2; ++mt) {
#pragma unroll
            for (int reg = 0; reg < 4; ++reg) {
                int mr = m0 + wm + mt * 16 + quad * 4 + reg;
                out[(size_t)mr * C_ + n] = acc[mt][nt][reg] + bv;
            }
        }
    }
}

// ---------------- MFMA flash attention v4: dbuf K/V + vectorized P-write ----------------
// vbt columns carry the within-64-key permutation s=(k%16)*4+k/16, so P's LDS
// storage (columns = s) packs each thread's 4 kt-values contiguously: b64 writes.
// Frag reads (P as A-op, Vt as B-op) remain b128 and contract consistently.
__global__ __launch_bounds__(256) void attn_mfma(const __bf16* __restrict__ qb,
                                                 const __bf16* __restrict__ kb,
                                                 const __bf16* __restrict__ vbt,
                                                 __bf16* __restrict__ ao) {
    __shared__ __bf16 Ks[2][64 * 64];
    __shared__ __bf16 Vts[2][64 * 64];
    __shared__ __bf16 Ps[4 * 32 * 72];

    const int tid = threadIdx.x;
    const int wave = tid >> 6, lane = tid & 63;
    const int lane15 = lane & 15, quad = lane >> 4;
    const int bh = blockIdx.x;
    const int qt = 7 - blockIdx.y;
    const int b = bh / H_, h = bh % H_;
    const int q0 = qt * 128;

    const __bf16* Kb = kb + (size_t)bh * T_ * D_;
    const __bf16* Vb = vbt + (size_t)bh * D_ * T_;
    __bf16* Pw = Ps + wave * 32 * 72;

    bf16x8 qf[2][2];
#pragma unroll
    for (int g = 0; g < 2; ++g) {
        const __bf16* qrow = qb + ((size_t)bh * T_ + q0 + wave * 32 + g * 16 + lane15) * D_ + quad * 8;
        qf[g][0] = *(const bf16x8*)qrow;
        qf[g][1] = *(const bf16x8*)(qrow + 32);
    }

    f32x4 o[2][4] = {};
    float lsum[2][4] = {};

    const int kunits = 2 * qt + 2;

#define ASTAGE(KU, BUF)                                                            \
    {                                                                              \
        const int k0s = (KU) * 64;                                                 \
        _Pragma("unroll")                                                          \
        for (int r = 0; r < 2; ++r) {                                              \
            int p = r * 256 + tid;                                                 \
            int row = p >> 3, c = p & 7;                                           \
            int cs = (c ^ (row & 7)) * 8;                                          \
            __builtin_amdgcn_global_load_lds(                                      \
                (gptr_t)(Kb + (size_t)(k0s + row) * D_ + cs),                      \
                (lptr_t)(&Ks[BUF][0] + (r * 256 + wave * 64) * 8), 16, 0, 0);      \
            __builtin_amdgcn_global_load_lds(                                      \
                (gptr_t)(Vb + (size_t)row * T_ + k0s + cs),                        \
                (lptr_t)(&Vts[BUF][0] + (r * 256 + wave * 64) * 8), 16, 0, 0);     \
        }                                                                          \
    }

    ASTAGE(0, 0);

    for (int ku = 0; ku < kunits; ++ku) {
        __syncthreads();
        if (ku + 1 < kunits) ASTAGE(ku + 1, (ku + 1) & 1);
        const __bf16* Kc = &Ks[ku & 1][0];
        const __bf16* Vc = &Vts[ku & 1][0];
        const int k0 = ku * 64;

        f32x4 s[2][4];
#pragma unroll
        for (int kt = 0; kt < 4; ++kt) {
            int row = kt * 16 + lane15;
            bf16x8 kf0 = *(const bf16x8*)(Kc + row * 64 + ((quad) ^ (row & 7)) * 8);
            bf16x8 kf1 = *(const bf16x8*)(Kc + row * 64 + ((4 + quad) ^ (row & 7)) * 8);
#pragma unroll
            for (int g = 0; g < 2; ++g) {
                f32x4 t = {};
                t = __builtin_amdgcn_mfma_f32_16x16x32_bf16(qf[g][0], kf0, t, 0, 0, 0);
                t = __builtin_amdgcn_mfma_f32_16x16x32_bf16(qf[g][1], kf1, t, 0, 0, 0);
                s[g][kt] = t;
            }
        }

        const bool diag = (ku >= 2 * qt);
#pragma unroll
        for (int g = 0; g < 2; ++g) {
#pragma unroll
            for (int r = 0; r < 4; ++r) {
                bf16x4 pk;
#pragma unroll
                for (int kt = 0; kt < 4; ++kt) {
                    int col = k0 + kt * 16 + lane15;
                    float p = __builtin_amdgcn_exp2f(s[g][kt][r]);
                    if (diag) {
                        int qrow = q0 + wave * 32 + g * 16 + quad * 4 + r;
                        if (col > qrow) p = 0.f;
                    }
                    lsum[g][r] += p;
                    pk[kt] = (__bf16)p;
                }
                // storage column = lane15*4 + kt  (matches vbt's permuted key order)
                *(bf16x4*)(Pw + (g * 16 + quad * 4 + r) * 72 + lane15 * 4) = pk;
            }
        }

        bf16x8 vf[4][2];
#pragma unroll
        for (int dt = 0; dt < 4; ++dt) {
            int row = dt * 16 + lane15;
#pragma unroll
            for (int half = 0; half < 2; ++half)
                vf[dt][half] = *(const bf16x8*)(Vc + row * 64 + ((half * 4 + quad) ^ (row & 7)) * 8);
        }
#pragma unroll
        for (int g = 0; g < 2; ++g) {
#pragma unroll
            for (int half = 0; half < 2; ++half) {
                bf16x8 pf = *(const bf16x8*)(Pw + (g * 16 + lane15) * 72 + half * 32 + quad * 8);
#pragma unroll
                for (int dt = 0; dt < 4; ++dt)
                    o[g][dt] = __builtin_amdgcn_mfma_f32_16x16x32_bf16(pf, vf[dt][half], o[g][dt], 0, 0, 0);
            }
        }
    }

#pragma unroll
    for (int g = 0; g < 2; ++g) {
        float inv[4];
#pragma unroll
        for (int r = 0; r < 4; ++r) {
            float ls = lsum[g][r];
            ls += __shfl_xor(ls, 1);
            ls += __shfl_xor(ls, 2);
            ls += __shfl_xor(ls, 4);
            ls += __shfl_xor(ls, 8);
            inv[r] = 1.0f / ls;
        }
#pragma unroll
        for (int dt = 0; dt < 4; ++dt) {
#pragma unroll
            for (int r = 0; r < 4; ++r) {
                int t = q0 + wave * 32 + g * 16 + quad * 4 + r;
                ao[((size_t)(b * T_ + t)) * C_ + h * 64 + dt * 16 + lane15] =
                    (__bf16)(o[g][dt][r] * inv[r]);
            }
        }
    }
}

extern "C" void kernel_launch(void* const* d_in, const int* in_sizes, int n_in,
                              void* d_out, int out_size, void* d_ws, size_t ws_size,
                              hipStream_t stream) {
    const float* x = (const float*)d_in[0];
    const float* w_attn = (const float*)d_in[1];
    const float* b_attn = (const float*)d_in[2];
    const float* w_proj = (const float*)d_in[3];
    const float* b_proj = (const float*)d_in[4];
    float* out = (float*)d_out;

    __bf16* xb = (__bf16*)d_ws;
    __bf16* wat = xb + (size_t)M_ * C_;
    __bf16* wpt = wat + (size_t)N3C * C_;
    __bf16* qb = wpt + (size_t)C_ * C_;         // pre-scaled by (1/8)log2e
    __bf16* kb = qb + (size_t)96 * T_ * D_;
    __bf16* vbt = kb + (size_t)96 * T_ * D_;    // [96][64][1024], permuted keys
    __bf16* ao = vbt + (size_t)96 * T_ * D_;

    prepass<<<5376, 256, 0, stream>>>(x, xb, w_attn, wat, w_proj, wpt);
    qkv_gemm_mfma<<<1152, 256, 0, stream>>>(xb, wat, b_attn, qb, kb, vbt);
    attn_mfma<<<dim3(96, 8), 256, 0, stream>>>(qb, kb, vbt, ao);
    proj_gemm_mfma<<<768, 256, 0, stream>>>(ao, wpt, b_proj, out);
}